// Round 5
// baseline (110.266 us; speedup 1.0000x reference)
//
#include <hip/hip_runtime.h>
#include <math.h>

#define TOPK 2048
#define NCLS 80      // reference: randint(0, 80)
#define NBIN 1024    // score-digest bins (uniform scores -> ~20/bin)
#define CMAX 2560    // candidate key capacity (K + tie-bin slack)
#define TN   512     // threads (8 waves)
#define CROWS 4      // output rows per block -> 512 blocks (2 per CU)

// ONE fused kernel, now sized for 2 blocks/CU (LDS ~78.7 KB < 80 KB):
// each block redundantly derives the COMPLETE top-K set in its own LDS and
// compares its CROWS output rows. Two co-resident blocks per CU hide each
// other's barrier/latency stalls (R4 at 108 KB LDS was 1 block/CU and
// latency-bound). binbase[] is eliminated by packing (base<<13 | cursor)
// into bincur -- the scatter atomicAdd(+1) only touches the cursor field.
struct P {
    const float* scores; const float* boxes; const int* classes;
    const float* sw1; const float* sb1; const float* sw2; const float* sb2;
    const float* sw3; const float* sb3;
    const float* lw1; const float* lb1; const float* lw2; const float* lb2;
    int M; int K;
    float* out_boxes; float* out_scores; float* out_cls;
};

__device__ __forceinline__ float iou_of(float xi, float yi, float ai,
                                        float x2i, float y2i, float4 bj) {
    float ix1 = fmaxf(xi, bj.x), iy1 = fmaxf(yi, bj.y);
    float ix2 = fminf(x2i, bj.x + bj.z), iy2 = fminf(y2i, bj.y + bj.w);
    float iw = fmaxf(ix2 - ix1, 0.0f), ih = fmaxf(iy2 - iy1, 0.0f);
    float inter = iw * ih;
    float uni = ai + bj.z * bj.w - inter;
    return inter / (uni + 1e-6f);
}

// monotone non-decreasing digest; single quantization used in all passes
__device__ __forceinline__ int digest10(float s) {
    int v = (int)(s * 1024.0f);
    return v < 0 ? 0 : (v > NBIN - 1 ? NBIN - 1 : v);
}

__device__ __forceinline__ float key_score(unsigned long long kk) {
    unsigned mono = (unsigned)(kk >> 32);
    unsigned ob = (mono & 0x80000000u) ? (mono & 0x7FFFFFFFu) : ~mono;
    return __uint_as_float(ob);
}

__global__ __launch_bounds__(TN, 4) void k_dacs(P p) {
    // ---- selection state (binned counting-rank; base/cursor packed) ----
    __shared__ int   bincur[NBIN];                // 4 KB: count -> (base<<13|cur)
    __shared__ unsigned long long skeys[CMAX];    // 20 KB candidate keys
    __shared__ int   sfx[TN];                     // 2 KB inclusive suffix sums
    __shared__ int   wsum[TN / 64];               // wave-total suffix sums
    __shared__ int   sh_cT;
    // ---- full selected set, per block ----
    __shared__ float4 sbox[TOPK];                 // 32 KB
    __shared__ float  sscore[TOPK];               // 8 KB
    __shared__ short  scls[TOPK];                 // 4 KB
    __shared__ short  clist[TOPK];                // 4 KB rows grouped by class
    __shared__ int    ccnt[NCLS], ccur[NCLS], cstart[NCLS + 1];
    __shared__ int    wtot;
    // ---- compare-phase state ----
    __shared__ float  swt[914];                   // sup MLP 801 + lambda 113
    __shared__ float  wpart[TN / 64];             // per-wave D partials
    __shared__ int    rowc[CROWS];
    __shared__ int    prefix[CROWS + 1];
    __shared__ float  Ssum[CROWS], Drow[CROWS];

    int tid = threadIdx.x, bid = blockIdx.x;
    int M = p.M, K = p.K, M4 = M >> 2;
    int r0 = bid * CROWS;
    int nrows = K - r0; if (nrows > CROWS) nrows = CROWS;
    if (nrows <= 0) return;                       // block-uniform, pre-barrier

    // ---- stage MLP weights early (independent loads overlap selection) ----
    for (int t = tid; t < 224; t += TN) swt[t] = p.sw1[t];
    if (tid < 32) swt[224 + tid] = p.sb1[tid];
    for (int t = tid; t < 512; t += TN) swt[256 + t] = p.sw2[t];
    if (tid < 16) swt[768 + tid] = p.sb2[tid];
    if (tid < 16) swt[784 + tid] = p.sw3[tid];
    if (tid == 0) swt[800] = p.sb3[0];
    if (tid < 80) swt[801 + tid] = p.lw1[tid];
    if (tid < 16) swt[881 + tid] = p.lb1[tid];
    if (tid < 16) swt[897 + tid] = p.lw2[tid];
    if (tid == 0) swt[913] = p.lb2[0];

    for (int b = tid; b < NBIN; b += TN) bincur[b] = 0;
    if (tid < NCLS) ccnt[tid] = 0;
    if (tid < CROWS) Ssum[tid] = 0.0f;
    __syncthreads();

    // ---- sweep 1: histogram straight from global (vectorized) ----
    const float4* s4p = (const float4*)p.scores;
    for (int i4 = tid; i4 < M4; i4 += TN) {
        float4 v = s4p[i4];
        atomicAdd(&bincur[digest10(v.x)], 1);
        atomicAdd(&bincur[digest10(v.y)], 1);
        atomicAdd(&bincur[digest10(v.z)], 1);
        atomicAdd(&bincur[digest10(v.w)], 1);
    }
    for (int i = M4 * 4 + tid; i < M; i += TN)
        atomicAdd(&bincur[digest10(p.scores[i])], 1);
    __syncthreads();

    // ---- suffix scan (shuffle-based): sfx[t] = sum of chunk sums t.. ----
    {
        const int BPT = NBIN / TN;                // 2 bins per thread
        int c0 = tid * BPT, sum = 0;
        #pragma unroll
        for (int u = 0; u < BPT; u++) sum += bincur[c0 + u];
        int lane = tid & 63;
        int x = sum;
        #pragma unroll
        for (int off = 1; off < 64; off <<= 1) {  // in-wave inclusive suffix
            int v = __shfl_down(x, off, 64);
            if (lane + off < 64) x += v;
        }
        if (lane == 0) wsum[tid >> 6] = x;        // wave totals (8)
        __syncthreads();
        if (tid < TN / 64) {                      // suffix over wave totals
            int t = wsum[tid];
            #pragma unroll
            for (int off = 1; off < TN / 64; off <<= 1) {
                int v = __shfl_down(t, off, 64);
                if (tid + off < TN / 64) t += v;
            }
            wsum[tid] = t;
        }
        __syncthreads();
        int wid = tid >> 6;
        int higher = (wid < TN / 64 - 1) ? wsum[wid + 1] : 0;
        sfx[tid] = x + higher;                    // global inclusive suffix
    }
    __syncthreads();

    // ---- pack (rank base << 13 | cursor=0) per bin + find crossing bin cT.
    //      Replaces the old binbase[] array AND the bincur=binbase copy pass.
    {
        const int BPT = NBIN / TN;
        int running = (tid < TN - 1) ? sfx[tid + 1] : 0;
        int c0 = tid * BPT;
        for (int u = BPT - 1; u >= 0; u--) {
            int b = c0 + u, cnt = bincur[b];
            if (running < K && running + cnt >= K) sh_cT = b;  // unique bin
            bincur[b] = (running << 13);          // base in high bits, cur=0
            running += cnt;
        }
    }
    __syncthreads();
    int cT = sh_cT;

    // ---- sweep 2 (from L2, vectorized): scatter candidate keys ----
    // key = monotonic(score bits) << 32 | (0xFFFFFFFF - i): descending key ==
    // descending score, ties -> lower index (stable top_k semantics).
    for (int i4 = tid; i4 < M4; i4 += TN) {
        float4 v = s4p[i4];
        #pragma unroll
        for (int u = 0; u < 4; u++) {
            float s = (u == 0) ? v.x : (u == 1) ? v.y : (u == 2) ? v.z : v.w;
            int d = digest10(s);
            if (d >= cT) {
                int i = i4 * 4 + u;
                int old = atomicAdd(&bincur[d], 1);           // bumps cursor
                int slot = (old >> 13) + (old & 8191);
                if (slot < CMAX) {
                    unsigned b = __float_as_uint(s);
                    b = (b & 0x80000000u) ? ~b : (b | 0x80000000u);
                    skeys[slot] = ((unsigned long long)b << 32) |
                                  (unsigned long long)(0xFFFFFFFFu - (unsigned)i);
                }
            }
        }
    }
    for (int i = M4 * 4 + tid; i < M; i += TN) {
        float s = p.scores[i];
        int d = digest10(s);
        if (d >= cT) {
            int old = atomicAdd(&bincur[d], 1);
            int slot = (old >> 13) + (old & 8191);
            if (slot < CMAX) {
                unsigned b = __float_as_uint(s);
                b = (b & 0x80000000u) ? ~b : (b | 0x80000000u);
                skeys[slot] = ((unsigned long long)b << 32) |
                              (unsigned long long)(0xFFFFFFFFu - (unsigned)i);
            }
        }
    }
    __syncthreads();

    // ---- exact rank within bin (~20 peers) + gather FULL set into LDS ----
    int pkT = bincur[cT];
    int C = (pkT >> 13) + (pkT & 8191); if (C > CMAX) C = CMAX;
    {
        const float4* boxes4 = (const float4*)p.boxes;
        for (int s = tid; s < C; s += TN) {
            unsigned long long ks = skeys[s];
            unsigned idx = 0xFFFFFFFFu - (unsigned)(ks & 0xFFFFFFFFull);
            float sc = key_score(ks);
            int d = digest10(sc);
            int pk = bincur[d];
            int st = pk >> 13;
            int en = st + (pk & 8191); if (en > CMAX) en = CMAX;
            int r = st;
            for (int t = st; t < en; t++) r += (skeys[t] > ks) ? 1 : 0;
            if (r < K) {
                sbox[r] = boxes4[idx];
                sscore[r] = sc;
                scls[r] = (short)p.classes[idx];
            }
        }
    }
    __syncthreads();

    // ---- per-class lists in LDS (verified 2-wave shuffle scan) ----
    for (int r = tid; r < K; r += TN) atomicAdd(&ccnt[scls[r]], 1);
    __syncthreads();
    {
        int x = 0, v = 0;
        if (tid < 128) {
            v = (tid < NCLS) ? ccnt[tid] : 0;
            x = v;
            #pragma unroll
            for (int off = 1; off < 64; off <<= 1) {
                int t = __shfl_up(x, off, 64);
                if ((tid & 63) >= off) x += t;
            }
            if (tid == 63) wtot = x;              // total of classes 0..63
        }
        __syncthreads();
        if (tid < NCLS) {
            int excl = x - v + ((tid >= 64) ? wtot : 0);
            ccur[tid] = excl;
            cstart[tid] = excl;
        }
        if (tid == 0) cstart[NCLS] = K;
        __syncthreads();
        for (int r = tid; r < K; r += TN) {
            int pos = atomicAdd(&ccur[scls[r]], 1);
            clist[pos] = (short)r;
        }
    }
    __syncthreads();

    // ---- Phase A: D row means; 2 waves per row, boxes from LDS ----
    {
        int wv = tid >> 6, lane = tid & 63;
        int row = wv >> 1, half = wv & 1;
        float dsum = 0.0f;
        if (row < nrows) {
            float4 bi = sbox[r0 + row];
            float ai = bi.z * bi.w, x2i = bi.x + bi.z, y2i = bi.y + bi.w;
            for (int j = lane + (half << 6); j < K; j += 128)
                dsum += iou_of(bi.x, bi.y, ai, x2i, y2i, sbox[j]);
            #pragma unroll
            for (int off = 32; off >= 1; off >>= 1)
                dsum += __shfl_xor(dsum, off, 64);
        }
        if (lane == 0) wpart[wv] = dsum;
    }

    // ---- per-row pair ranges ----
    if (tid < CROWS) {
        int st = 0, cnt = 0;
        if (tid < nrows) {
            int c = scls[r0 + tid];
            st = cstart[c];
            cnt = cstart[c + 1] - st;
        }
        rowc[tid] = st;
        prefix[tid] = cnt;                        // temp: counts
    }
    __syncthreads();
    if (tid < nrows) Drow[tid] = (wpart[2 * tid] + wpart[2 * tid + 1]) / (float)K;
    if (tid == 0) {                               // CROWS-element exclusive prefix
        int acc = 0;
        #pragma unroll
        for (int rr = 0; rr < CROWS; rr++) { int t = prefix[rr]; prefix[rr] = acc; acc += t; }
        prefix[CROWS] = acc;
    }
    __syncthreads();

    int Pb = prefix[CROWS];
    const float* W1 = swt;       const float* B1 = swt + 224;
    const float* W2 = swt + 256; const float* B2 = swt + 768;
    const float* W3 = swt + 784; float B3 = swt[800];

    // ---- Phase B: flat per-pair fused MLP (same-class pairs only) ----
    for (int pp = tid; pp < Pb; pp += TN) {
        int lo = 0, hi = CROWS;
        while (hi - lo > 1) {
            int mid = (lo + hi) >> 1;
            if (prefix[mid] <= pp) lo = mid; else hi = mid;
        }
        int row = lo;
        int j = (int)clist[rowc[row] + (pp - prefix[row])];
        float4 bi = sbox[r0 + row];
        float4 bj = sbox[j];
        float ai = bi.z * bi.w, x2i = bi.x + bi.z, y2i = bi.y + bi.w;
        float iou = iou_of(bi.x, bi.y, ai, x2i, y2i, bj);
        float f1 = fabsf(bi.x - bj.x), f2 = fabsf(bi.y - bj.y);
        float f3 = fabsf(bi.z - bj.z), f4 = fabsf(bi.w - bj.w);
        float f5 = sscore[r0 + row], f6 = sscore[j];
        float acc2[16];
        #pragma unroll
        for (int q = 0; q < 16; q++) acc2[q] = B2[q];
        #pragma unroll 2
        for (int o = 0; o < 32; o++) {
            float a = B1[o];
            a += iou * W1[0 * 32 + o];
            a += f1 * W1[1 * 32 + o];
            a += f2 * W1[2 * 32 + o];
            a += f3 * W1[3 * 32 + o];
            a += f4 * W1[4 * 32 + o];
            a += f5 * W1[5 * 32 + o];
            a += f6 * W1[6 * 32 + o];
            float h = fmaxf(a, 0.0f);
            #pragma unroll
            for (int q = 0; q < 16; q++) acc2[q] += h * W2[o * 16 + q];
        }
        float acc3 = B3;
        #pragma unroll
        for (int q = 0; q < 16; q++) acc3 += fmaxf(acc2[q], 0.0f) * W3[q];
        atomicAdd(&Ssum[row], iou / (1.0f + expf(-acc3)));
    }
    __syncthreads();

    // ---- finale: lambda MLP + outputs for this block's rows ----
    if (tid < nrows) {
        int r = r0 + tid;
        float4 bi = sbox[r];
        float si = sscore[r];
        const float* LW1 = swt + 801; const float* LB1 = swt + 881;
        const float* LW2 = swt + 897; float LB2 = swt[913];
        float in5[5] = { bi.x, bi.y, bi.z, bi.w, si };
        float acc = LB2;
        #pragma unroll
        for (int o = 0; o < 16; o++) {
            float a2 = LB1[o];
            #pragma unroll
            for (int f = 0; f < 5; f++) a2 += in5[f] * LW1[f * 16 + o];
            acc += fmaxf(a2, 0.0f) * LW2[o];
        }
        float lam = 1.0f / (1.0f + expf(-acc));
        ((float4*)p.out_boxes)[r] = bi;
        p.out_cls[r] = (float)scls[r];
        p.out_scores[r] = si * expf(-lam * Ssum[tid] * Drow[tid]);
    }
}

extern "C" void kernel_launch(void* const* d_in, const int* in_sizes, int n_in,
                              void* d_out, int out_size, void* d_ws, size_t ws_size,
                              hipStream_t stream) {
    int M = in_sizes[1];
    int K = (M < TOPK) ? M : TOPK;

    P dp;
    dp.scores  = (const float*)d_in[1];
    dp.boxes   = (const float*)d_in[0];
    dp.classes = (const int*)d_in[2];
    dp.sw1 = (const float*)d_in[3];  dp.sb1 = (const float*)d_in[4];
    dp.sw2 = (const float*)d_in[5];  dp.sb2 = (const float*)d_in[6];
    dp.sw3 = (const float*)d_in[7];  dp.sb3 = (const float*)d_in[8];
    dp.lw1 = (const float*)d_in[9];  dp.lb1 = (const float*)d_in[10];
    dp.lw2 = (const float*)d_in[11]; dp.lb2 = (const float*)d_in[12];
    dp.M = M; dp.K = K;
    dp.out_boxes  = (float*)d_out;
    dp.out_scores = (float*)d_out + (size_t)K * 4;
    dp.out_cls    = (float*)d_out + (size_t)K * 5;

    int nb = (K + CROWS - 1) / CROWS;
    k_dacs<<<nb, TN, 0, stream>>>(dp);
}

// Round 6
// 106.914 us; speedup vs baseline: 1.0314x; 1.0314x over previous
//
#include <hip/hip_runtime.h>
#include <math.h>

#define TOPK 2048
#define NCLS 80      // reference: randint(0, 80)
#define NBIN 4096    // score-digest bins (uniform scores -> ~5/bin)
#define CMAX 2560    // candidate key capacity (K + tie-bin slack)
#define TNA  1024    // kA threads (histogram + scan, one block)
#define TND  512     // kD threads (compare)
#define CROWS 4      // kD rows per block -> 512 blocks (2 per CU)

// Distributed selection pipeline (R6): selection is done ONCE, spread over
// the grid, instead of redundantly per compare-block (R4/R5 burned ~50% of
// their VALU work on 256-512 redundant full-M sweeps).
//   kA (1 block):  LDS histogram of all M scores + suffix scan -> writes
//                  packed (rank_base<<16 | cursor=0) per bin to ghist and
//                  the threshold bin cT to gmeta.
//   kB (20 blks):  distributed scatter: candidates (bin >= cT) bump the
//                  global per-bin cursor, write 64-bit sort key to gskeys.
//   kC (10 blks):  distributed exact rank (~5 peers/bin) + gather: writes
//                  selB/selS/selC[rank] (the top-K set, 48 KB, L2-resident).
//   kD (512 blks): compare phase per CROWS rows: D row-means from L2,
//                  per-row same-class list by LDS compaction (no global
//                  clist), flat per-pair MLP, lambda, outputs.
// Cross-kernel visibility: global writes are visible at kernel boundaries;
// packing cursor in low 16 bits keeps base+cursor exact for any bin count
// <= 65535 (M = 20000).

struct SelAP { const float* scores; int M; int K; int* ghist; int* gmeta; };
struct ScatP { const float* scores; int M; int* ghist; const int* gmeta;
               unsigned long long* gskeys; };
struct RankP { const float* boxes; const int* classes; const int* ghist;
               const int* gmeta; const unsigned long long* gskeys; int K;
               float4* selB; float* selS; int* selC; };
struct CmpP  { const float4* selB; const float* selS; const int* selC;
               const float* sw1; const float* sb1; const float* sw2; const float* sb2;
               const float* sw3; const float* sb3;
               const float* lw1; const float* lb1; const float* lw2; const float* lb2;
               int K;
               float* out_boxes; float* out_scores; float* out_cls; };

__device__ __forceinline__ float iou_of(float xi, float yi, float ai,
                                        float x2i, float y2i, float4 bj) {
    float ix1 = fmaxf(xi, bj.x), iy1 = fmaxf(yi, bj.y);
    float ix2 = fminf(x2i, bj.x + bj.z), iy2 = fminf(y2i, bj.y + bj.w);
    float iw = fmaxf(ix2 - ix1, 0.0f), ih = fmaxf(iy2 - iy1, 0.0f);
    float inter = iw * ih;
    float uni = ai + bj.z * bj.w - inter;
    return inter / (uni + 1e-6f);
}

// monotone non-decreasing digest; single quantization used in all passes
__device__ __forceinline__ int digest12(float s) {
    int v = (int)(s * 4096.0f);
    return v < 0 ? 0 : (v > NBIN - 1 ? NBIN - 1 : v);
}

__device__ __forceinline__ unsigned long long make_key(float s, unsigned i) {
    unsigned b = __float_as_uint(s);
    b = (b & 0x80000000u) ? ~b : (b | 0x80000000u);
    return ((unsigned long long)b << 32) |
           (unsigned long long)(0xFFFFFFFFu - i);
}

__device__ __forceinline__ float key_score(unsigned long long kk) {
    unsigned mono = (unsigned)(kk >> 32);
    unsigned ob = (mono & 0x80000000u) ? (mono & 0x7FFFFFFFu) : ~mono;
    return __uint_as_float(ob);
}

// ---------------------------------------------------------------------------
// kA: one block. LDS histogram (verified R4 code path) + shuffle suffix scan
// (verified R3/R4) -> packed bases to ghist, threshold bin to gmeta.
// ---------------------------------------------------------------------------
__global__ __launch_bounds__(TNA, 1) void k_selA(SelAP p) {
    __shared__ int lbin[NBIN];                    // 16 KB counts
    __shared__ int sfx[TNA];                      // 4 KB inclusive suffix sums
    __shared__ int wsum[TNA / 64];
    __shared__ int sh_cT;

    int tid = threadIdx.x;
    int M = p.M, K = p.K, M4 = M >> 2;

    for (int b = tid; b < NBIN; b += TNA) lbin[b] = 0;
    __syncthreads();

    const float4* s4p = (const float4*)p.scores;
    for (int i4 = tid; i4 < M4; i4 += TNA) {
        float4 v = s4p[i4];
        atomicAdd(&lbin[digest12(v.x)], 1);
        atomicAdd(&lbin[digest12(v.y)], 1);
        atomicAdd(&lbin[digest12(v.z)], 1);
        atomicAdd(&lbin[digest12(v.w)], 1);
    }
    for (int i = M4 * 4 + tid; i < M; i += TNA)
        atomicAdd(&lbin[digest12(p.scores[i])], 1);
    __syncthreads();

    // suffix scan: sfx[t] = sum of per-thread chunk sums t..
    {
        const int BPT = NBIN / TNA;               // 4 bins per thread
        int c0 = tid * BPT, sum = 0;
        #pragma unroll
        for (int u = 0; u < BPT; u++) sum += lbin[c0 + u];
        int lane = tid & 63;
        int x = sum;
        #pragma unroll
        for (int off = 1; off < 64; off <<= 1) {
            int v = __shfl_down(x, off, 64);
            if (lane + off < 64) x += v;
        }
        if (lane == 0) wsum[tid >> 6] = x;
        __syncthreads();
        if (tid < TNA / 64) {
            int t = wsum[tid];
            #pragma unroll
            for (int off = 1; off < TNA / 64; off <<= 1) {
                int v = __shfl_down(t, off, 64);
                if (tid + off < TNA / 64) t += v;
            }
            wsum[tid] = t;
        }
        __syncthreads();
        int wid = tid >> 6;
        int higher = (wid < TNA / 64 - 1) ? wsum[wid + 1] : 0;
        sfx[tid] = x + higher;
    }
    __syncthreads();

    // packed (base << 16 | cursor=0) per bin straight to global + find cT
    {
        const int BPT = NBIN / TNA;
        int running = (tid < TNA - 1) ? sfx[tid + 1] : 0;
        int c0 = tid * BPT;
        for (int u = BPT - 1; u >= 0; u--) {
            int b = c0 + u, cnt = lbin[b];
            if (running < K && running + cnt >= K) sh_cT = b;  // unique bin
            p.ghist[b] = (running << 16);
            running += cnt;
        }
    }
    __syncthreads();
    if (tid == 0) p.gmeta[0] = sh_cT;
}

// ---------------------------------------------------------------------------
// kB: distributed scatter of candidate keys (global cursor per bin).
// key = monotonic(score bits)<<32 | (0xFFFFFFFF - i): descending key ==
// descending score, ties -> lower index (stable top_k semantics).
// ---------------------------------------------------------------------------
__global__ void k_scat(ScatP p) {
    int nt = gridDim.x * blockDim.x;
    int gt = blockIdx.x * blockDim.x + threadIdx.x;
    int cT = p.gmeta[0];
    int M = p.M, M4 = M >> 2;
    const float4* s4p = (const float4*)p.scores;
    for (int i4 = gt; i4 < M4; i4 += nt) {
        float4 v = s4p[i4];
        #pragma unroll
        for (int u = 0; u < 4; u++) {
            float s = (u == 0) ? v.x : (u == 1) ? v.y : (u == 2) ? v.z : v.w;
            int d = digest12(s);
            if (d >= cT) {
                int old = atomicAdd(&p.ghist[d], 1);          // bumps cursor
                int slot = (old >> 16) + (old & 0xFFFF);
                if (slot < CMAX)
                    p.gskeys[slot] = make_key(s, (unsigned)(i4 * 4 + u));
            }
        }
    }
    for (int i = M4 * 4 + gt; i < M; i += nt) {
        float s = p.scores[i];
        int d = digest12(s);
        if (d >= cT) {
            int old = atomicAdd(&p.ghist[d], 1);
            int slot = (old >> 16) + (old & 0xFFFF);
            if (slot < CMAX) p.gskeys[slot] = make_key(s, (unsigned)i);
        }
    }
}

// ---------------------------------------------------------------------------
// kC: distributed exact rank within bin (~5 peers) + gather the top-K set.
// ---------------------------------------------------------------------------
__global__ void k_rank(RankP p) {
    int t = blockIdx.x * blockDim.x + threadIdx.x;
    int cT = p.gmeta[0];
    int pkT = p.ghist[cT];
    int C = (pkT >> 16) + (pkT & 0xFFFF); if (C > CMAX) C = CMAX;
    if (t >= C) return;
    unsigned long long ks = p.gskeys[t];
    unsigned idx = 0xFFFFFFFFu - (unsigned)(ks & 0xFFFFFFFFull);
    float sc = key_score(ks);
    int d = digest12(sc);
    int pk = p.ghist[d];
    int st = pk >> 16;
    int en = st + (pk & 0xFFFF); if (en > CMAX) en = CMAX;
    int r = st;
    for (int q = st; q < en; q++) r += (p.gskeys[q] > ks) ? 1 : 0;
    if (r < p.K) {
        p.selB[r] = ((const float4*)p.boxes)[idx];
        p.selS[r] = sc;
        p.selC[r] = p.classes[idx];
    }
}

// ---------------------------------------------------------------------------
// kD: compare phase. 512 blocks x 4 rows, 512 threads, ~20 KB LDS ->
// high occupancy. Sel arrays read straight from L2 (proven R2). Same-class
// peer lists built per block by LDS compaction (no global clist).
// ---------------------------------------------------------------------------
__global__ __launch_bounds__(TND, 2) void k_cmp(CmpP p) {
    __shared__ float swt[914];                    // sup MLP 801 + lambda 113
    __shared__ short mlist[CROWS * TOPK];         // 16 KB same-class peers
    __shared__ int   mcnt[CROWS];
    __shared__ int   rowcls[CROWS];
    __shared__ int   prefix[CROWS + 1];
    __shared__ float wpart[TND / 64];
    __shared__ float Ssum[CROWS], Drow[CROWS];

    int tid = threadIdx.x, bid = blockIdx.x;
    int K = p.K;
    int r0 = bid * CROWS;
    int nrows = K - r0; if (nrows > CROWS) nrows = CROWS;
    if (nrows <= 0) return;                       // block-uniform, pre-barrier

    // ---- stage MLP weights ----
    for (int t = tid; t < 224; t += TND) swt[t] = p.sw1[t];
    if (tid < 32) swt[224 + tid] = p.sb1[tid];
    for (int t = tid; t < 512; t += TND) swt[256 + t] = p.sw2[t];
    if (tid < 16) swt[768 + tid] = p.sb2[tid];
    if (tid < 16) swt[784 + tid] = p.sw3[tid];
    if (tid == 0) swt[800] = p.sb3[0];
    if (tid < 80) swt[801 + tid] = p.lw1[tid];
    if (tid < 16) swt[881 + tid] = p.lb1[tid];
    if (tid < 16) swt[897 + tid] = p.lw2[tid];
    if (tid == 0) swt[913] = p.lb2[0];

    if (tid < CROWS) {
        mcnt[tid] = 0;
        Ssum[tid] = 0.0f;
        rowcls[tid] = (tid < nrows) ? p.selC[r0 + tid] : -1;  // -1 matches none
    }
    __syncthreads();

    // ---- same-class compaction: one pass over selC, push matching j ----
    for (int j = tid; j < K; j += TND) {
        int c = p.selC[j];
        #pragma unroll
        for (int rr = 0; rr < CROWS; rr++) {
            if (c == rowcls[rr]) {
                int pos = atomicAdd(&mcnt[rr], 1);
                mlist[rr * TOPK + pos] = (short)j;
            }
        }
    }

    // ---- Phase A: D row means; 2 waves per row, boxes from L2 ----
    {
        int wv = tid >> 6, lane = tid & 63;
        int row = wv >> 1, half = wv & 1;
        float dsum = 0.0f;
        if (row < nrows) {
            float4 bi = p.selB[r0 + row];
            float ai = bi.z * bi.w, x2i = bi.x + bi.z, y2i = bi.y + bi.w;
            for (int j = lane + (half << 6); j < K; j += 128)
                dsum += iou_of(bi.x, bi.y, ai, x2i, y2i, p.selB[j]);
            #pragma unroll
            for (int off = 32; off >= 1; off >>= 1)
                dsum += __shfl_xor(dsum, off, 64);
        }
        if (lane == 0) wpart[wv] = dsum;
    }
    __syncthreads();
    if (tid < nrows) Drow[tid] = (wpart[2 * tid] + wpart[2 * tid + 1]) / (float)K;
    if (tid == 0) {                               // exclusive prefix of mcnt
        int acc = 0;
        #pragma unroll
        for (int rr = 0; rr < CROWS; rr++) { int t = mcnt[rr]; prefix[rr] = acc; acc += t; }
        prefix[CROWS] = acc;
    }
    __syncthreads();

    int Pb = prefix[CROWS];
    const float* W1 = swt;       const float* B1 = swt + 224;
    const float* W2 = swt + 256; const float* B2 = swt + 768;
    const float* W3 = swt + 784; float B3 = swt[800];

    // ---- Phase B: flat per-pair fused MLP over compacted pair list ----
    for (int pp = tid; pp < Pb; pp += TND) {
        int row = (pp >= prefix[1]) + (pp >= prefix[2]) + (pp >= prefix[3]);
        int j = (int)mlist[row * TOPK + (pp - prefix[row])];
        float4 bi = p.selB[r0 + row];
        float4 bj = p.selB[j];
        float ai = bi.z * bi.w, x2i = bi.x + bi.z, y2i = bi.y + bi.w;
        float iou = iou_of(bi.x, bi.y, ai, x2i, y2i, bj);
        float f1 = fabsf(bi.x - bj.x), f2 = fabsf(bi.y - bj.y);
        float f3 = fabsf(bi.z - bj.z), f4 = fabsf(bi.w - bj.w);
        float f5 = p.selS[r0 + row], f6 = p.selS[j];
        float acc2[16];
        #pragma unroll
        for (int q = 0; q < 16; q++) acc2[q] = B2[q];
        #pragma unroll 2
        for (int o = 0; o < 32; o++) {
            float a = B1[o];
            a += iou * W1[0 * 32 + o];
            a += f1 * W1[1 * 32 + o];
            a += f2 * W1[2 * 32 + o];
            a += f3 * W1[3 * 32 + o];
            a += f4 * W1[4 * 32 + o];
            a += f5 * W1[5 * 32 + o];
            a += f6 * W1[6 * 32 + o];
            float h = fmaxf(a, 0.0f);
            #pragma unroll
            for (int q = 0; q < 16; q++) acc2[q] += h * W2[o * 16 + q];
        }
        float acc3 = B3;
        #pragma unroll
        for (int q = 0; q < 16; q++) acc3 += fmaxf(acc2[q], 0.0f) * W3[q];
        atomicAdd(&Ssum[row], iou / (1.0f + expf(-acc3)));
    }
    __syncthreads();

    // ---- finale: lambda MLP + outputs for this block's rows ----
    if (tid < nrows) {
        int r = r0 + tid;
        float4 bi = p.selB[r];
        float si = p.selS[r];
        const float* LW1 = swt + 801; const float* LB1 = swt + 881;
        const float* LW2 = swt + 897; float LB2 = swt[913];
        float in5[5] = { bi.x, bi.y, bi.z, bi.w, si };
        float acc = LB2;
        #pragma unroll
        for (int o = 0; o < 16; o++) {
            float a2 = LB1[o];
            #pragma unroll
            for (int f = 0; f < 5; f++) a2 += in5[f] * LW1[f * 16 + o];
            acc += fmaxf(a2, 0.0f) * LW2[o];
        }
        float lam = 1.0f / (1.0f + expf(-acc));
        ((float4*)p.out_boxes)[r] = bi;
        p.out_cls[r] = (float)p.selC[r];
        p.out_scores[r] = si * expf(-lam * Ssum[tid] * Drow[tid]);
    }
}

extern "C" void kernel_launch(void* const* d_in, const int* in_sizes, int n_in,
                              void* d_out, int out_size, void* d_ws, size_t ws_size,
                              hipStream_t stream) {
    int M = in_sizes[1];
    int K = (M < TOPK) ? M : TOPK;

    char* ws = (char*)d_ws;
    float4* selB  = (float4*)ws;               ws += (size_t)TOPK * 16;  // 16B aligned
    float*  selS  = (float*)ws;                ws += (size_t)TOPK * 4;
    int*    selC  = (int*)ws;                  ws += (size_t)TOPK * 4;
    unsigned long long* gskeys = (unsigned long long*)ws; ws += (size_t)CMAX * 8;
    int*    ghist = (int*)ws;                  ws += (size_t)NBIN * 4;
    int*    gmeta = (int*)ws;                  ws += 16;

    SelAP a;
    a.scores = (const float*)d_in[1];
    a.M = M; a.K = K; a.ghist = ghist; a.gmeta = gmeta;

    ScatP b;
    b.scores = (const float*)d_in[1];
    b.M = M; b.ghist = ghist; b.gmeta = gmeta; b.gskeys = gskeys;

    RankP c;
    c.boxes = (const float*)d_in[0];
    c.classes = (const int*)d_in[2];
    c.ghist = ghist; c.gmeta = gmeta; c.gskeys = gskeys; c.K = K;
    c.selB = selB; c.selS = selS; c.selC = selC;

    CmpP d;
    d.selB = selB; d.selS = selS; d.selC = selC;
    d.sw1 = (const float*)d_in[3];  d.sb1 = (const float*)d_in[4];
    d.sw2 = (const float*)d_in[5];  d.sb2 = (const float*)d_in[6];
    d.sw3 = (const float*)d_in[7];  d.sb3 = (const float*)d_in[8];
    d.lw1 = (const float*)d_in[9];  d.lb1 = (const float*)d_in[10];
    d.lw2 = (const float*)d_in[11]; d.lb2 = (const float*)d_in[12];
    d.K = K;
    d.out_boxes  = (float*)d_out;
    d.out_scores = (float*)d_out + (size_t)K * 4;
    d.out_cls    = (float*)d_out + (size_t)K * 5;

    int nbB = ((M >> 2) + 255) / 256; if (nbB < 1) nbB = 1;
    int nbC = (CMAX + 255) / 256;
    int nbD = (K + CROWS - 1) / CROWS;

    k_selA<<<1, TNA, 0, stream>>>(a);
    k_scat<<<nbB, 256, 0, stream>>>(b);
    k_rank<<<nbC, 256, 0, stream>>>(c);
    k_cmp <<<nbD, TND, 0, stream>>>(d);
}

// Round 7
// 105.746 us; speedup vs baseline: 1.0427x; 1.0110x over previous
//
#include <hip/hip_runtime.h>
#include <math.h>

#define TOPK 2048
#define NCLS 80      // reference: randint(0, 80)
#define NBIN 4096    // score-digest bins (uniform scores -> ~5/bin)
#define CMAX 2560    // candidate key capacity (K + tie-bin slack)
#define TNS  1024    // k_sel threads (ONE block)
#define TND  512     // k_cmp threads
#define CROWS 4      // k_cmp rows per block -> 512 blocks

// R7: 2 launches, zero redundancy.
//  k_sel (ONE 1024-thread block): full selection in LDS -- histogram,
//    shuffle suffix scan, packed (base<<16|cursor) bins, candidate scatter,
//    exact rank (~5 peers/bin), gather top-K to global selB/S/C, and the
//    per-class list build (cstart/clist). Selection is ~45K LDS ops + two
//    80 KB sweeps: cheap on one CU; it was only ever expensive when
//    repeated per block (R3: x32, R5: x512) or split across launches (R6:
//    3 extra ~5us launch gaps).
//  k_cmp (512 blocks x 512 thr, CROWS=4): compare phase from L2 (R2/R6
//    verified), global clist (no per-block compaction), bj-shared Phase A.
struct SelP {
    const float* scores; const float* boxes; const int* classes;
    int M; int K;
    float4* selB; float* selS; int* selC;
    int* cstart;      // [NCLS+1]
    short* clist;     // [K] rows grouped by class
};

struct CmpP {
    const float4* selB; const float* selS; const int* selC;
    const int* cstart; const short* clist;
    const float* sw1; const float* sb1; const float* sw2; const float* sb2;
    const float* sw3; const float* sb3;
    const float* lw1; const float* lb1; const float* lw2; const float* lb2;
    int K;
    float* out_boxes; float* out_scores; float* out_cls;
};

__device__ __forceinline__ float iou_of(float xi, float yi, float ai,
                                        float x2i, float y2i, float4 bj) {
    float ix1 = fmaxf(xi, bj.x), iy1 = fmaxf(yi, bj.y);
    float ix2 = fminf(x2i, bj.x + bj.z), iy2 = fminf(y2i, bj.y + bj.w);
    float iw = fmaxf(ix2 - ix1, 0.0f), ih = fmaxf(iy2 - iy1, 0.0f);
    float inter = iw * ih;
    float uni = ai + bj.z * bj.w - inter;
    return inter / (uni + 1e-6f);
}

// monotone non-decreasing digest; single quantization used in all passes
__device__ __forceinline__ int digest12(float s) {
    int v = (int)(s * 4096.0f);
    return v < 0 ? 0 : (v > NBIN - 1 ? NBIN - 1 : v);
}

__device__ __forceinline__ unsigned long long make_key(float s, unsigned i) {
    unsigned b = __float_as_uint(s);
    b = (b & 0x80000000u) ? ~b : (b | 0x80000000u);
    return ((unsigned long long)b << 32) |
           (unsigned long long)(0xFFFFFFFFu - i);
}

__device__ __forceinline__ float key_score(unsigned long long kk) {
    unsigned mono = (unsigned)(kk >> 32);
    unsigned ob = (mono & 0x80000000u) ? (mono & 0x7FFFFFFFu) : ~mono;
    return __uint_as_float(ob);
}

// ---------------------------------------------------------------------------
// k_sel: ONE block, complete selection + class lists. All sub-phases are
// the verified code paths from R3-R6 (hist/scan: kA; packed-cursor scatter:
// R5/R6; rank+gather: R3; class lists: R2).
// ---------------------------------------------------------------------------
__global__ __launch_bounds__(TNS, 1) void k_sel(SelP p) {
    __shared__ int   bincur[NBIN];                // 16 KB: count->(base<<16|cur)
    __shared__ unsigned long long skeys[CMAX];    // 20 KB candidate keys
    __shared__ int   sfx[TNS];                    // 4 KB inclusive suffix sums
    __shared__ int   wsum[TNS / 64];
    __shared__ int   sh_cT;
    __shared__ short scls[TOPK];                  // 4 KB class per rank
    __shared__ int   ccnt[NCLS], ccur[NCLS];
    __shared__ int   wtot;

    int tid = threadIdx.x;
    int M = p.M, K = p.K, M4 = M >> 2;

    for (int b = tid; b < NBIN; b += TNS) bincur[b] = 0;
    if (tid < NCLS) ccnt[tid] = 0;
    __syncthreads();

    // ---- sweep 1: histogram (vectorized) ----
    const float4* s4p = (const float4*)p.scores;
    for (int i4 = tid; i4 < M4; i4 += TNS) {
        float4 v = s4p[i4];
        atomicAdd(&bincur[digest12(v.x)], 1);
        atomicAdd(&bincur[digest12(v.y)], 1);
        atomicAdd(&bincur[digest12(v.z)], 1);
        atomicAdd(&bincur[digest12(v.w)], 1);
    }
    for (int i = M4 * 4 + tid; i < M; i += TNS)
        atomicAdd(&bincur[digest12(p.scores[i])], 1);
    __syncthreads();

    // ---- suffix scan (shuffle-based): sfx[t] = sum of chunk sums t.. ----
    {
        const int BPT = NBIN / TNS;               // 4 bins per thread
        int c0 = tid * BPT, sum = 0;
        #pragma unroll
        for (int u = 0; u < BPT; u++) sum += bincur[c0 + u];
        int lane = tid & 63;
        int x = sum;
        #pragma unroll
        for (int off = 1; off < 64; off <<= 1) {  // in-wave inclusive suffix
            int v = __shfl_down(x, off, 64);
            if (lane + off < 64) x += v;
        }
        if (lane == 0) wsum[tid >> 6] = x;        // wave totals (16)
        __syncthreads();
        if (tid < TNS / 64) {                     // suffix over wave totals
            int t = wsum[tid];
            #pragma unroll
            for (int off = 1; off < TNS / 64; off <<= 1) {
                int v = __shfl_down(t, off, 64);
                if (tid + off < TNS / 64) t += v;
            }
            wsum[tid] = t;
        }
        __syncthreads();
        int wid = tid >> 6;
        int higher = (wid < TNS / 64 - 1) ? wsum[wid + 1] : 0;
        sfx[tid] = x + higher;                    // global inclusive suffix
    }
    __syncthreads();

    // ---- pack (base << 16 | cursor=0) per bin + find crossing bin cT ----
    {
        const int BPT = NBIN / TNS;
        int running = (tid < TNS - 1) ? sfx[tid + 1] : 0;
        int c0 = tid * BPT;
        for (int u = BPT - 1; u >= 0; u--) {
            int b = c0 + u, cnt = bincur[b];
            if (running < K && running + cnt >= K) sh_cT = b;  // unique bin
            bincur[b] = (running << 16);
            running += cnt;
        }
    }
    __syncthreads();
    int cT = sh_cT;

    // ---- sweep 2: scatter candidate keys (bin >= cT) ----
    // key = monotonic(score bits)<<32 | (0xFFFFFFFF - i): descending key ==
    // descending score, ties -> lower index (stable top_k semantics).
    for (int i4 = tid; i4 < M4; i4 += TNS) {
        float4 v = s4p[i4];
        #pragma unroll
        for (int u = 0; u < 4; u++) {
            float s = (u == 0) ? v.x : (u == 1) ? v.y : (u == 2) ? v.z : v.w;
            int d = digest12(s);
            if (d >= cT) {
                int old = atomicAdd(&bincur[d], 1);           // bumps cursor
                int slot = (old >> 16) + (old & 0xFFFF);
                if (slot < CMAX)
                    skeys[slot] = make_key(s, (unsigned)(i4 * 4 + u));
            }
        }
    }
    for (int i = M4 * 4 + tid; i < M; i += TNS) {
        float s = p.scores[i];
        int d = digest12(s);
        if (d >= cT) {
            int old = atomicAdd(&bincur[d], 1);
            int slot = (old >> 16) + (old & 0xFFFF);
            if (slot < CMAX) skeys[slot] = make_key(s, (unsigned)i);
        }
    }
    __syncthreads();

    // ---- exact rank within bin (~5 peers) + gather top-K to global ----
    int pkT = bincur[cT];
    int C = (pkT >> 16) + (pkT & 0xFFFF); if (C > CMAX) C = CMAX;
    {
        const float4* boxes4 = (const float4*)p.boxes;
        for (int s = tid; s < C; s += TNS) {
            unsigned long long ks = skeys[s];
            unsigned idx = 0xFFFFFFFFu - (unsigned)(ks & 0xFFFFFFFFull);
            float sc = key_score(ks);
            int d = digest12(sc);
            int pk = bincur[d];
            int st = pk >> 16;
            int en = st + (pk & 0xFFFF); if (en > CMAX) en = CMAX;
            int r = st;
            for (int t = st; t < en; t++) r += (skeys[t] > ks) ? 1 : 0;
            if (r < K) {
                int c = p.classes[idx];
                p.selB[r] = boxes4[idx];
                p.selS[r] = sc;
                p.selC[r] = c;
                scls[r] = (short)c;               // LDS copy for list build
            }
        }
    }
    __syncthreads();

    // ---- per-class lists (verified 2-wave shuffle scan, R2) ----
    for (int r = tid; r < K; r += TNS) atomicAdd(&ccnt[scls[r]], 1);
    __syncthreads();
    {
        int x = 0, v = 0;
        if (tid < 128) {
            v = (tid < NCLS) ? ccnt[tid] : 0;
            x = v;
            #pragma unroll
            for (int off = 1; off < 64; off <<= 1) {
                int t = __shfl_up(x, off, 64);
                if ((tid & 63) >= off) x += t;
            }
            if (tid == 63) wtot = x;              // total of classes 0..63
        }
        __syncthreads();
        if (tid < NCLS) {
            int excl = x - v + ((tid >= 64) ? wtot : 0);
            ccur[tid] = excl;
            p.cstart[tid] = excl;
        }
        if (tid == 0) p.cstart[NCLS] = K;
        __syncthreads();
        for (int r = tid; r < K; r += TNS) {
            int pos = atomicAdd(&ccur[scls[r]], 1);
            p.clist[pos] = (short)r;
        }
    }
}

// ---------------------------------------------------------------------------
// k_cmp: 512 blocks x 4 rows, 512 threads, (512,4) -> 2 blocks/CU (R5-proven
// no-spill regime for this MLP body: VGPR=64). Sel arrays + clist read
// straight from L2. Phase A shares each bj load across all 4 rows.
// ---------------------------------------------------------------------------
__global__ __launch_bounds__(TND, 4) void k_cmp(CmpP p) {
    __shared__ float swt[914];                    // sup MLP 801 + lambda 113
    __shared__ float wpart[(TND / 64) * CROWS];   // 8 waves x 4 rows
    __shared__ int   rowc[CROWS];
    __shared__ int   prefix[CROWS + 1];
    __shared__ float Ssum[CROWS], Drow[CROWS];

    int tid = threadIdx.x, bid = blockIdx.x;
    int K = p.K;
    int r0 = bid * CROWS;
    int nrows = K - r0; if (nrows > CROWS) nrows = CROWS;
    if (nrows <= 0) return;                       // block-uniform, pre-barrier

    // ---- stage MLP weights ----
    for (int t = tid; t < 224; t += TND) swt[t] = p.sw1[t];
    if (tid < 32) swt[224 + tid] = p.sb1[tid];
    for (int t = tid; t < 512; t += TND) swt[256 + t] = p.sw2[t];
    if (tid < 16) swt[768 + tid] = p.sb2[tid];
    if (tid < 16) swt[784 + tid] = p.sw3[tid];
    if (tid == 0) swt[800] = p.sb3[0];
    if (tid < 80) swt[801 + tid] = p.lw1[tid];
    if (tid < 16) swt[881 + tid] = p.lb1[tid];
    if (tid < 16) swt[897 + tid] = p.lw2[tid];
    if (tid == 0) swt[913] = p.lb2[0];

    if (tid < CROWS) {
        Ssum[tid] = 0.0f;
        int st = 0, cnt = 0;
        if (tid < nrows) {
            int c = p.selC[r0 + tid];
            st = p.cstart[c];
            cnt = p.cstart[c + 1] - st;
        }
        rowc[tid] = st;
        prefix[tid] = cnt;                        // temp: counts
    }
    __syncthreads();
    if (tid == 0) {                               // exclusive prefix of counts
        int acc = 0;
        #pragma unroll
        for (int rr = 0; rr < CROWS; rr++) { int t = prefix[rr]; prefix[rr] = acc; acc += t; }
        prefix[CROWS] = acc;
    }

    // ---- Phase A: D row means; each bj load feeds all 4 rows ----
    {
        float4 b0 = p.selB[r0];
        float4 b1 = (nrows > 1) ? p.selB[r0 + 1] : b0;
        float4 b2 = (nrows > 2) ? p.selB[r0 + 2] : b0;
        float4 b3 = (nrows > 3) ? p.selB[r0 + 3] : b0;
        float a0 = b0.z * b0.w, x20 = b0.x + b0.z, y20 = b0.y + b0.w;
        float a1 = b1.z * b1.w, x21 = b1.x + b1.z, y21 = b1.y + b1.w;
        float a2 = b2.z * b2.w, x22 = b2.x + b2.z, y22 = b2.y + b2.w;
        float a3 = b3.z * b3.w, x23 = b3.x + b3.z, y23 = b3.y + b3.w;
        float d0 = 0.0f, d1 = 0.0f, d2 = 0.0f, d3 = 0.0f;
        for (int j = tid; j < K; j += TND) {
            float4 bj = p.selB[j];
            d0 += iou_of(b0.x, b0.y, a0, x20, y20, bj);
            d1 += iou_of(b1.x, b1.y, a1, x21, y21, bj);
            d2 += iou_of(b2.x, b2.y, a2, x22, y22, bj);
            d3 += iou_of(b3.x, b3.y, a3, x23, y23, bj);
        }
        #pragma unroll
        for (int off = 32; off >= 1; off >>= 1) {
            d0 += __shfl_xor(d0, off, 64);
            d1 += __shfl_xor(d1, off, 64);
            d2 += __shfl_xor(d2, off, 64);
            d3 += __shfl_xor(d3, off, 64);
        }
        int lane = tid & 63, wv = tid >> 6;
        if (lane == 0) {
            wpart[wv * CROWS + 0] = d0;
            wpart[wv * CROWS + 1] = d1;
            wpart[wv * CROWS + 2] = d2;
            wpart[wv * CROWS + 3] = d3;
        }
    }
    __syncthreads();
    if (tid < nrows) {
        float s = 0.0f;
        #pragma unroll
        for (int wv = 0; wv < TND / 64; wv++) s += wpart[wv * CROWS + tid];
        Drow[tid] = s / (float)K;
    }

    int Pb = prefix[CROWS];
    const float* W1 = swt;       const float* B1 = swt + 224;
    const float* W2 = swt + 256; const float* B2 = swt + 768;
    const float* W3 = swt + 784; float B3 = swt[800];

    // ---- Phase B: flat per-pair fused MLP (j from global clist) ----
    for (int pp = tid; pp < Pb; pp += TND) {
        int row = (pp >= prefix[1]) + (pp >= prefix[2]) + (pp >= prefix[3]);
        int j = (int)p.clist[rowc[row] + (pp - prefix[row])];
        float4 bi = p.selB[r0 + row];
        float4 bj = p.selB[j];
        float ai = bi.z * bi.w, x2i = bi.x + bi.z, y2i = bi.y + bi.w;
        float iou = iou_of(bi.x, bi.y, ai, x2i, y2i, bj);
        float f1 = fabsf(bi.x - bj.x), f2 = fabsf(bi.y - bj.y);
        float f3 = fabsf(bi.z - bj.z), f4 = fabsf(bi.w - bj.w);
        float f5 = p.selS[r0 + row], f6 = p.selS[j];
        float acc2[16];
        #pragma unroll
        for (int q = 0; q < 16; q++) acc2[q] = B2[q];
        #pragma unroll 2
        for (int o = 0; o < 32; o++) {
            float a = B1[o];
            a += iou * W1[0 * 32 + o];
            a += f1 * W1[1 * 32 + o];
            a += f2 * W1[2 * 32 + o];
            a += f3 * W1[3 * 32 + o];
            a += f4 * W1[4 * 32 + o];
            a += f5 * W1[5 * 32 + o];
            a += f6 * W1[6 * 32 + o];
            float h = fmaxf(a, 0.0f);
            #pragma unroll
            for (int q = 0; q < 16; q++) acc2[q] += h * W2[o * 16 + q];
        }
        float acc3 = B3;
        #pragma unroll
        for (int q = 0; q < 16; q++) acc3 += fmaxf(acc2[q], 0.0f) * W3[q];
        atomicAdd(&Ssum[row], iou / (1.0f + expf(-acc3)));
    }
    __syncthreads();

    // ---- finale: lambda MLP + outputs for this block's rows ----
    if (tid < nrows) {
        int r = r0 + tid;
        float4 bi = p.selB[r];
        float si = p.selS[r];
        const float* LW1 = swt + 801; const float* LB1 = swt + 881;
        const float* LW2 = swt + 897; float LB2 = swt[913];
        float in5[5] = { bi.x, bi.y, bi.z, bi.w, si };
        float acc = LB2;
        #pragma unroll
        for (int o = 0; o < 16; o++) {
            float a2 = LB1[o];
            #pragma unroll
            for (int f = 0; f < 5; f++) a2 += in5[f] * LW1[f * 16 + o];
            acc += fmaxf(a2, 0.0f) * LW2[o];
        }
        float lam = 1.0f / (1.0f + expf(-acc));
        ((float4*)p.out_boxes)[r] = bi;
        p.out_cls[r] = (float)p.selC[r];
        p.out_scores[r] = si * expf(-lam * Ssum[tid] * Drow[tid]);
    }
}

extern "C" void kernel_launch(void* const* d_in, const int* in_sizes, int n_in,
                              void* d_out, int out_size, void* d_ws, size_t ws_size,
                              hipStream_t stream) {
    int M = in_sizes[1];
    int K = (M < TOPK) ? M : TOPK;

    char* ws = (char*)d_ws;
    float4* selB   = (float4*)ws;              ws += (size_t)TOPK * 16;
    float*  selS   = (float*)ws;               ws += (size_t)TOPK * 4;
    int*    selC   = (int*)ws;                 ws += (size_t)TOPK * 4;
    int*    cstart = (int*)ws;                 ws += (size_t)(NCLS + 2) * 4;
    short*  clist  = (short*)ws;               ws += (size_t)TOPK * 2;

    SelP sp;
    sp.scores  = (const float*)d_in[1];
    sp.boxes   = (const float*)d_in[0];
    sp.classes = (const int*)d_in[2];
    sp.M = M; sp.K = K;
    sp.selB = selB; sp.selS = selS; sp.selC = selC;
    sp.cstart = cstart; sp.clist = clist;

    CmpP cp;
    cp.selB = selB; cp.selS = selS; cp.selC = selC;
    cp.cstart = cstart; cp.clist = clist;
    cp.sw1 = (const float*)d_in[3];  cp.sb1 = (const float*)d_in[4];
    cp.sw2 = (const float*)d_in[5];  cp.sb2 = (const float*)d_in[6];
    cp.sw3 = (const float*)d_in[7];  cp.sb3 = (const float*)d_in[8];
    cp.lw1 = (const float*)d_in[9];  cp.lb1 = (const float*)d_in[10];
    cp.lw2 = (const float*)d_in[11]; cp.lb2 = (const float*)d_in[12];
    cp.K = K;
    cp.out_boxes  = (float*)d_out;
    cp.out_scores = (float*)d_out + (size_t)K * 4;
    cp.out_cls    = (float*)d_out + (size_t)K * 5;

    k_sel<<<1, TNS, 0, stream>>>(sp);
    k_cmp<<<(K + CROWS - 1) / CROWS, TND, 0, stream>>>(cp);
}